// Round 6
// baseline (1010.837 us; speedup 1.0000x reference)
//
#include <hip/hip_runtime.h>
#include <hip/hip_fp16.h>

// Sparse conv3x3x3 (3->64) + BN + ReLU + sparse conv3x3x3 (64->3), N=1M.
// R5: fp16-packed conv1 (fixes VGPR remat: 41 half2 regs vs 81 f32) +
//     compacted per-k pair lists for conv2 (only ~4.8/27 valid -> 5.6x less
//     work; wave-uniform k keeps W2 in SGPRs; BN+ReLU inline in packed fp16
//     so the 55us apply pass disappears; scatter via 3 f32 atomics/pair).

#define KVOL 27
#define CHID 64

typedef _Float16 half2_t __attribute__((ext_vector_type(2)));
typedef unsigned int uint32;
typedef unsigned long long u64;

static __device__ __forceinline__ float fdot2(uint32 u, uint32 w, float acc) {
    return __builtin_amdgcn_fdot2(__builtin_bit_cast(half2_t, u),
                                  __builtin_bit_cast(half2_t, w), acc, false);
}
static __device__ __forceinline__ uint32 pkh2(float a, float b) {  // RTZ pack
    auto p = __builtin_amdgcn_cvt_pkrtz(a, b);
    return __builtin_bit_cast(uint32, p);
}
static __device__ __forceinline__ uint32 pk_rne(float a, float b) { // RNE pack
    _Float16 ha = (_Float16)a, hb = (_Float16)b;
    unsigned short ua = __builtin_bit_cast(unsigned short, ha);
    unsigned short ub = __builtin_bit_cast(unsigned short, hb);
    return (uint32)ua | ((uint32)ub << 16);
}
static __device__ __forceinline__ void unpk(uint32 u, float& lo, float& hi) {
    half2_t h = __builtin_bit_cast(half2_t, u);
    lo = (float)h.x; hi = (float)h.y;
}
// packed fp16 BN + ReLU: relu(h*sc+sh) elementwise on a half2 word
static __device__ __forceinline__ uint32 bnrelu(uint32 h, uint32 sc, uint32 sh) {
    half2_t r = __builtin_bit_cast(half2_t, h) * __builtin_bit_cast(half2_t, sc)
              + __builtin_bit_cast(half2_t, sh);
    uint32 u = __builtin_bit_cast(uint32, r);
    uint32 s = (u & 0x80008000u) >> 15;      // 0/1 per half where negative
    return u & ~(s * 0xFFFFu);               // zero negative halves
}

// meta layout (u32 index into meta block)
#define M_GSTATS 0     // f32[128]
#define M_CNT8   128   // u32[8*27]
#define M_STARTS 344   // u32[28]  (64-aligned, STARTS[27]=total P)
#define M_ENDS   372   // u32[27]
#define M_CURSOR 399   // u32[27]
#define M_SCPK   426   // u32[32]
#define M_SHPK   458   // u32[32]
#define M_WORDS  490

__global__ __launch_bounds__(256) void k_prep(
    const float* __restrict__ feats, const float* __restrict__ W1,
    const float* __restrict__ W2,
    float* __restrict__ f_t, uint32* __restrict__ w1q, uint32* __restrict__ w2q,
    uint32* __restrict__ h2, int N, int Ns)
{
    const int b = blockIdx.x;
    if (b == 0) {
        // w1q[d][p] = half2(W1t[d][2p], W1t[d][2p+1]); W1 is [81][64]
        for (int i = threadIdx.x; i < 64 * 41; i += 256) {
            const int d = i / 41, p = i % 41;
            const int kc0 = 2 * p, kc1 = 2 * p + 1;
            const float v0 = W1[kc0 * 64 + d];
            const float v1 = (kc1 < 81) ? W1[kc1 * 64 + d] : 0.f;
            w1q[i] = pk_rne(v0, v1);
        }
        // w2q[k][dc][c][p] = half2(W2[26-k][8dc+2p][c], W2[26-k][8dc+2p+1][c])
        for (int i = threadIdx.x; i < KVOL * 96; i += 256) {
            const int k = i / 96, r = i % 96;
            const int dc = r / 12, c = (r % 12) / 4, p = r & 3;
            const int d0 = dc * 8 + 2 * p;
            const float* src = W2 + (26 - k) * 192;
            w2q[i] = pk_rne(src[d0 * 3 + c], src[(d0 + 1) * 3 + c]);
        }
        for (int i = threadIdx.x; i < 3 * 64; i += 256) {     // f_t zero pad
            const int c = i >> 6, pp = i & 63;
            f_t[(long long)c * Ns + N + pp] = 0.f;
        }
        for (int i = threadIdx.x; i < 8 * 4; i += 256) {      // h2 zero pad row N
            const int dc = i >> 2, p = i & 3;
            h2[((long long)dc * Ns + N) * 4 + p] = 0u;
        }
    } else {
        __shared__ float tile[768];
        for (long long t0 = (long long)(b - 1) * 256; t0 < N;
             t0 += (long long)(gridDim.x - 1) * 256) {
            const int nrem = (int)min((long long)256, (long long)N - t0);
            __syncthreads();
            for (int i = threadIdx.x; i < 3 * nrem; i += 256)
                tile[i] = feats[t0 * 3 + i];
            __syncthreads();
            for (int i = threadIdx.x; i < nrem; i += 256) {
                f_t[0 * (long long)Ns + t0 + i] = tile[i * 3 + 0];
                f_t[1 * (long long)Ns + t0 + i] = tile[i * 3 + 1];
                f_t[2 * (long long)Ns + t0 + i] = tile[i * 3 + 2];
            }
        }
    }
}

__global__ __launch_bounds__(256, 4) void k_conv1(
    const float* __restrict__ f_t, const uint32* __restrict__ w1q,
    const int* __restrict__ nbr, uint32* __restrict__ h2,
    uint32* __restrict__ cnt8, int N, int Ns)
{
    __shared__ uint32 lcnt[KVOL];
    if (threadIdx.x < KVOL) lcnt[threadIdx.x] = 0;
    __syncthreads();

    const int lane = threadIdx.x & 63;
    const int tile = (int)((blockIdx.x * 256u + threadIdx.x) >> 6);
    const long long n0 = (long long)tile * 64;
    const bool active = (n0 < N);          // wave-uniform (N % 64 == 0)

    if (active) {
        const int n = (int)(n0 + lane);
        int j[KVOL];
#pragma unroll
        for (int k = 0; k < KVOL; ++k) {
            const int jr = nbr[(long long)k * N + n];   // coalesced burst
            const u64 m = __ballot(jr >= 0);
            if (lane == 0) atomicAdd(&lcnt[k], (uint32)__popcll(m));
            j[k] = (jr < 0) ? N : jr;                   // zero-row redirect
        }

        uint32 fh[41];                     // packed half2 gather (41 regs)
#pragma unroll
        for (int p = 0; p < 41; ++p) {
            const int kc0 = 2 * p, kc1 = 2 * p + 1;
            const float x0 = f_t[(long long)(kc0 % 3) * Ns + j[kc0 / 3]];
            const float x1 = (kc1 < 81)
                ? f_t[(long long)(kc1 % 3) * Ns + j[kc1 / 3]] : 0.f;
            fh[p] = pkh2(x0, x1);
        }

#pragma unroll 2
        for (int t = 0; t < 32; ++t) {                // channel-pair sweep
            const uint32* __restrict__ w0 = w1q + (2 * t) * 41;      // s_load
            const uint32* __restrict__ w1 = w1q + (2 * t + 1) * 41;
            float a0 = 0.f, a1 = 0.f;
#pragma unroll
            for (int p = 0; p < 41; ++p) {
                a0 = fdot2(fh[p], w0[p], a0);
                a1 = fdot2(fh[p], w1[p], a1);
            }
            h2[((long long)(t >> 2) * Ns + n) * 4 + (t & 3)] = pkh2(a0, a1);
        }
    }

    __syncthreads();
    if (threadIdx.x < KVOL)
        atomicAdd(&cnt8[(blockIdx.x & 7) * KVOL + threadIdx.x], lcnt[threadIdx.x]);
}

__global__ __launch_bounds__(256) void k_stats(
    const uint32* __restrict__ h2, float* __restrict__ gstats, int N, int Ns)
{
    const int dc = blockIdx.y;
    const uint4* base = (const uint4*)(h2 + (long long)dc * Ns * 4);
    float s[8], q[8];
#pragma unroll
    for (int e = 0; e < 8; ++e) { s[e] = 0.f; q[e] = 0.f; }
    for (long long i = blockIdx.x * 256 + threadIdx.x; i < N;
         i += (long long)gridDim.x * 256) {
        const uint4 u = base[i];
        float lo, hi;
        unpk(u.x, lo, hi); s[0]+=lo; q[0]=fmaf(lo,lo,q[0]); s[1]+=hi; q[1]=fmaf(hi,hi,q[1]);
        unpk(u.y, lo, hi); s[2]+=lo; q[2]=fmaf(lo,lo,q[2]); s[3]+=hi; q[3]=fmaf(hi,hi,q[3]);
        unpk(u.z, lo, hi); s[4]+=lo; q[4]=fmaf(lo,lo,q[4]); s[5]+=hi; q[5]=fmaf(hi,hi,q[5]);
        unpk(u.w, lo, hi); s[6]+=lo; q[6]=fmaf(lo,lo,q[6]); s[7]+=hi; q[7]=fmaf(hi,hi,q[7]);
    }
#pragma unroll
    for (int e = 0; e < 8; ++e)
        for (int off = 32; off > 0; off >>= 1) {
            s[e] += __shfl_down(s[e], off);
            q[e] += __shfl_down(q[e], off);
        }
    __shared__ float red[4][16];
    const int wib = threadIdx.x >> 6, lane = threadIdx.x & 63;
    if (lane == 0) {
#pragma unroll
        for (int e = 0; e < 8; ++e) { red[wib][e] = s[e]; red[wib][8 + e] = q[e]; }
    }
    __syncthreads();
    if (threadIdx.x < 16) {
        const float v = red[0][threadIdx.x] + red[1][threadIdx.x]
                      + red[2][threadIdx.x] + red[3][threadIdx.x];
        const int e = threadIdx.x & 7;
        const int d = dc * 8 + e;
        atomicAdd(&gstats[threadIdx.x < 8 ? d : 64 + d], v);
    }
}

// one block, 64 threads: BN params (packed fp16) + segment starts/ends/cursors
__global__ void k_scan(uint32* __restrict__ meta,
                       const float* __restrict__ gamma,
                       const float* __restrict__ beta, float invN)
{
    __shared__ float scv[64], shv[64];
    __shared__ uint32 scnt[KVOL];
    const int t = threadIdx.x;
    if (t < KVOL) {
        uint32 c = 0;
        for (int r = 0; r < 8; ++r) c += meta[M_CNT8 + r * KVOL + t];
        scnt[t] = c;
    }
    {   // BN
        const float* gstats = (const float*)meta;
        const float mu  = gstats[t] * invN;
        const float var = gstats[64 + t] * invN - mu * mu;
        const float sc  = gamma[t] * rsqrtf(var + 1e-5f);
        scv[t] = sc;
        shv[t] = beta[t] - mu * sc;
    }
    __syncthreads();
    if (t == 0) {
        uint32 s = 0;
        for (int k = 0; k < KVOL; ++k) {
            meta[M_STARTS + k] = s;
            meta[M_CURSOR + k] = s;
            meta[M_ENDS + k]   = s + scnt[k];
            s += (scnt[k] + 63u) & ~63u;     // 64-align each segment
        }
        meta[M_STARTS + KVOL] = s;           // total P
    }
    if (t < 32) {
        meta[M_SCPK + t] = pk_rne(scv[2 * t], scv[2 * t + 1]);
        meta[M_SHPK + t] = pk_rne(shv[2 * t], shv[2 * t + 1]);
    }
}

// compacted (n,j) pair lists per k; ordered within each 2048-chunk
__global__ __launch_bounds__(256) void k_fill(
    const int* __restrict__ nbr, uint32* __restrict__ meta,
    int2* __restrict__ pairs, int N, uint32 cap)
{
    __shared__ int lbuf[2048];
    __shared__ uint32 wcnt[4];
    __shared__ uint32 sbase, srun;
    const int k = blockIdx.y;
    const int nb = blockIdx.x * 2048;
    const int tid = threadIdx.x;
    const int wib = tid >> 6, lane = tid & 63;

    uint32 mycnt = 0;
#pragma unroll
    for (int r = 0; r < 8; ++r) {
        const int i = nb + r * 256 + tid;
        const int v = (i < N) ? nbr[(long long)k * N + i] : -1;
        lbuf[r * 256 + tid] = v;
        mycnt += (v >= 0);
    }
    // block total
    for (int off = 32; off > 0; off >>= 1) mycnt += __shfl_down(mycnt, off);
    if (lane == 0) wcnt[wib] = mycnt;
    __syncthreads();
    if (tid == 0) {
        const uint32 C = wcnt[0] + wcnt[1] + wcnt[2] + wcnt[3];
        sbase = atomicAdd(&meta[M_CURSOR + k], C);
        srun = 0;
    }
    __syncthreads();
    const uint32 base = sbase;

    for (int r = 0; r < 8; ++r) {
        const int i = r * 256 + tid;
        const int jv = lbuf[i];
        const bool v = (jv >= 0);
        const u64 m = __ballot(v);
        if (lane == 0) wcnt[wib] = (uint32)__popcll(m);
        __syncthreads();
        uint32 woff = srun;
        for (int w = 0; w < 4; ++w) if (w < wib) woff += wcnt[w];
        const uint32 pos = woff + (uint32)__popcll(m & ((1ull << lane) - 1ull));
        if (v && base + pos < cap)
            pairs[base + pos] = make_int2(nb + i, jv);
        __syncthreads();
        if (tid == 0) srun += wcnt[0] + wcnt[1] + wcnt[2] + wcnt[3];
        __syncthreads();
    }
}

__global__ __launch_bounds__(256) void k_conv2(
    const uint32* __restrict__ h2, const uint32* __restrict__ w2q,
    const uint32* __restrict__ meta, const int2* __restrict__ pairs,
    float* __restrict__ out, int N, int Ns)
{
    const int lane = threadIdx.x & 63;
    const int wid = (blockIdx.x << 2) + (threadIdx.x >> 6);
    const int nwv = gridDim.x << 2;
    const uint32 P = meta[M_STARTS + KVOL];

    uint32 scl[32], shl[32];
#pragma unroll
    for (int i = 0; i < 32; ++i) { scl[i] = meta[M_SCPK + i]; shl[i] = meta[M_SHPK + i]; }

    for (uint32 base = (uint32)wid * 64u; base < P; base += (uint32)nwv * 64u) {
        int k = 0;                                    // wave-uniform search
        while (k < KVOL - 1 && base >= meta[M_STARTS + k + 1]) ++k;
        const uint32 send = meta[M_ENDS + k];
        const uint32 idx = base + lane;
        const bool act = idx < send;
        int n = 0, j = N;
        if (act) { const int2 pr = pairs[idx]; n = pr.x; j = pr.y; }

        uint4 u[8];
#pragma unroll
        for (int dc = 0; dc < 8; ++dc)
            u[dc] = *(const uint4*)(h2 + ((long long)dc * Ns + j) * 4);

        const uint32* __restrict__ w = w2q + k * 96;  // uniform -> s_load
        float a0 = 0.f, a1 = 0.f, a2 = 0.f;
#pragma unroll
        for (int dc = 0; dc < 8; ++dc) {
            const int wb = dc * 12, sb = dc * 4;
            const uint32 h0 = bnrelu(u[dc].x, scl[sb + 0], shl[sb + 0]);
            const uint32 h1 = bnrelu(u[dc].y, scl[sb + 1], shl[sb + 1]);
            const uint32 h2w = bnrelu(u[dc].z, scl[sb + 2], shl[sb + 2]);
            const uint32 h3 = bnrelu(u[dc].w, scl[sb + 3], shl[sb + 3]);
            a0 = fdot2(h0, w[wb + 0], a0);
            a1 = fdot2(h0, w[wb + 4], a1);
            a2 = fdot2(h0, w[wb + 8], a2);
            a0 = fdot2(h1, w[wb + 1], a0);
            a1 = fdot2(h1, w[wb + 5], a1);
            a2 = fdot2(h1, w[wb + 9], a2);
            a0 = fdot2(h2w, w[wb + 2], a0);
            a1 = fdot2(h2w, w[wb + 6], a1);
            a2 = fdot2(h2w, w[wb + 10], a2);
            a0 = fdot2(h3, w[wb + 3], a0);
            a1 = fdot2(h3, w[wb + 7], a1);
            a2 = fdot2(h3, w[wb + 11], a2);
        }
        if (act) {
            atomicAdd(&out[3LL * n + 0], a0);
            atomicAdd(&out[3LL * n + 1], a1);
            atomicAdd(&out[3LL * n + 2], a2);
        }
    }
}

extern "C" void kernel_launch(void* const* d_in, const int* in_sizes, int n_in,
                              void* d_out, int out_size, void* d_ws, size_t ws_size,
                              hipStream_t stream) {
    const float* feats = (const float*)d_in[0];
    const float* W1    = (const float*)d_in[1];
    const float* gamma = (const float*)d_in[2];
    const float* beta  = (const float*)d_in[3];
    const float* W2    = (const float*)d_in[4];
    const int*   nbr   = (const int*)  d_in[5];
    const int N  = in_sizes[0] / 3;
    const int Ns = N + 64;
    float* out = (float*)d_out;

    char* ws = (char*)d_ws;
    uint32* h2 = (uint32*)ws;                                   // 8*Ns*16 B
    size_t off = (size_t)8 * Ns * 16;
    uint32* w2q = (uint32*)(ws + off); off += KVOL * 96 * 4;    // 10.4 KB
    uint32* meta = (uint32*)(ws + off); off += ((M_WORDS * 4 + 255) & ~255ull);
    // f_t/w1q region overlaps pairs (f_t,w1q dead before k_fill writes pairs)
    float*  f_t = (float*)(ws + off);
    uint32* w1q = (uint32*)(ws + off + (size_t)3 * Ns * 4);
    int2*   pairs = (int2*)(ws + off);
    const uint32 cap = (uint32)((ws_size - off) / sizeof(int2));

    (void)hipMemsetAsync(meta, 0, (M_CNT8 + 8 * KVOL) * 4, stream); // gstats+cnt8
    (void)hipMemsetAsync(out, 0, (size_t)out_size * 4, stream);

    const int nblk = (N / 64 + 3) / 4;            // 3907
    k_prep <<<257, 256, 0, stream>>>(feats, W1, W2, f_t, w1q, w2q, h2, N, Ns);
    k_conv1<<<nblk, 256, 0, stream>>>(f_t, w1q, nbr, h2, (uint32*)(meta + M_CNT8), N, Ns);
    k_stats<<<dim3(256, 8), 256, 0, stream>>>(h2, (float*)meta, N, Ns);
    k_scan <<<1, 64, 0, stream>>>(meta, gamma, beta, 1.0f / (float)N);
    k_fill <<<dim3((N + 2047) / 2048, KVOL), 256, 0, stream>>>(nbr, meta, pairs, N, cap);
    k_conv2<<<2048, 256, 0, stream>>>(h2, w2q, meta, pairs, out, N, Ns);
}

// Round 7
// 578.655 us; speedup vs baseline: 1.7469x; 1.7469x over previous
//
#include <hip/hip_runtime.h>
#include <hip/hip_fp16.h>

// Sparse conv3x3x3 (3->64) + BN + ReLU + sparse conv3x3x3 (64->3), N=1M.
// R6: revert R5's pair-compaction (it destroyed gather locality: FETCH
//     298MB->1.2GB). Dense-n waves + zero-pad-row redirect, with:
//  - h stored ROW-major fp16 [N+1][64]: a valid conv2 gather = ONE fully
//    utilized 128B line/lane (chunked layout: 8x16B fragments of 8 lines).
//  - conv1 packs the f-gather to fp16 half2 (41 words, no f32[81] remat;
//    R5 showed VGPR=52 => compiler re-gathered inside the channel sweep),
//    inner loop = v_dot2_f32_f16 vs uniform s_loaded weights.
//  - BN+ReLU as a separate streaming pass (f32 math), conv2 = pure dot2.

#define KVOL 27

typedef _Float16 half2_t __attribute__((ext_vector_type(2)));
typedef unsigned int uint32;

static __device__ __forceinline__ float fdot2(uint32 u, uint32 w, float acc) {
    return __builtin_amdgcn_fdot2(__builtin_bit_cast(half2_t, u),
                                  __builtin_bit_cast(half2_t, w), acc, false);
}
static __device__ __forceinline__ uint32 pkh2(float a, float b) {  // RTZ pack
    auto p = __builtin_amdgcn_cvt_pkrtz(a, b);
    return __builtin_bit_cast(uint32, p);
}
static __device__ __forceinline__ uint32 pk_rne(float a, float b) { // RNE pack
    _Float16 ha = (_Float16)a, hb = (_Float16)b;
    unsigned short ua = __builtin_bit_cast(unsigned short, ha);
    unsigned short ub = __builtin_bit_cast(unsigned short, hb);
    return (uint32)ua | ((uint32)ub << 16);
}
static __device__ __forceinline__ void unpk(uint32 u, float& lo, float& hi) {
    half2_t h = __builtin_bit_cast(half2_t, u);
    lo = (float)h.x; hi = (float)h.y;
}

__global__ __launch_bounds__(256) void k_prep(
    const float* __restrict__ feats, const float* __restrict__ W1,
    const float* __restrict__ W2,
    float* __restrict__ f_t, uint32* __restrict__ w1q, uint32* __restrict__ w2q,
    uint32* __restrict__ h32, int N, int Ns)
{
    const int b = blockIdx.x;
    if (b == 0) {
        // w1q[d][p] = half2(W1[2p][d], W1[2p+1][d]); W1 flat [81][64]
        for (int i = threadIdx.x; i < 64 * 41; i += 256) {
            const int d = i / 41, p = i % 41;
            const int kc0 = 2 * p, kc1 = 2 * p + 1;
            const float v0 = W1[kc0 * 64 + d];
            const float v1 = (kc1 < 81) ? W1[kc1 * 64 + d] : 0.f;
            w1q[i] = pk_rne(v0, v1);
        }
        // w2q[k][g][c][p] = half2(W2[26-k][8g+2p][c], W2[26-k][8g+2p+1][c])
        for (int i = threadIdx.x; i < KVOL * 96; i += 256) {
            const int k = i / 96, r = i % 96;
            const int g = r / 12, c = (r % 12) / 4, p = r & 3;
            const int d0 = g * 8 + 2 * p;
            const float* src = W2 + (26 - k) * 192;
            w2q[i] = pk_rne(src[d0 * 3 + c], src[(d0 + 1) * 3 + c]);
        }
        for (int i = threadIdx.x; i < 3 * 64; i += 256) {     // f_t zero pad
            const int c = i >> 6, pp = i & 63;
            f_t[(long long)c * Ns + N + pp] = 0.f;
        }
        if (threadIdx.x < 32)                                 // h zero pad row N
            h32[(long long)N * 32 + threadIdx.x] = 0u;
    } else {
        __shared__ float tile[768];
        for (long long t0 = (long long)(b - 1) * 256; t0 < N;
             t0 += (long long)(gridDim.x - 1) * 256) {
            const int nrem = (int)min((long long)256, (long long)N - t0);
            __syncthreads();
            for (int i = threadIdx.x; i < 3 * nrem; i += 256)
                tile[i] = feats[t0 * 3 + i];
            __syncthreads();
            for (int i = threadIdx.x; i < nrem; i += 256) {
                f_t[0 * (long long)Ns + t0 + i] = tile[i * 3 + 0];
                f_t[1 * (long long)Ns + t0 + i] = tile[i * 3 + 1];
                f_t[2 * (long long)Ns + t0 + i] = tile[i * 3 + 2];
            }
        }
    }
}

__global__ __launch_bounds__(256, 4) void k_conv1(
    const float* __restrict__ f_t, const uint32* __restrict__ w1q,
    const int* __restrict__ nbr, uint32* __restrict__ h32,
    int N, int Ns)
{
    const int lane = threadIdx.x & 63;
    const int tile = (int)((blockIdx.x * 256u + threadIdx.x) >> 6);
    const long long n0 = (long long)tile * 64;
    if (n0 >= N) return;                    // wave-uniform (N%64==0)
    const int n = (int)(n0 + lane);

    int j[KVOL];
#pragma unroll
    for (int k = 0; k < KVOL; ++k) j[k] = nbr[(long long)k * N + n]; // coalesced
#pragma unroll
    for (int k = 0; k < KVOL; ++k) j[k] = (j[k] < 0) ? N : j[k];     // zero-row

    uint32 fh[41];                          // fp16-packed gather
#pragma unroll
    for (int p = 0; p < 41; ++p) {
        const int kc0 = 2 * p, kc1 = 2 * p + 1;
        const float x0 = f_t[(long long)(kc0 % 3) * Ns + j[kc0 / 3]];
        const float x1 = (kc1 < 81)
            ? f_t[(long long)(kc1 % 3) * Ns + j[kc1 / 3]] : 0.f;
        fh[p] = pkh2(x0, x1);
    }

    uint32* __restrict__ hrow = h32 + (long long)n * 32;
#pragma unroll
    for (int g = 0; g < 8; ++g) {           // 8 words of the row per group
        uint32 wd[4];
#pragma unroll
        for (int p4 = 0; p4 < 4; ++p4) {
            const int t = 4 * g + p4;       // word t = channels (2t, 2t+1)
            const uint32* __restrict__ w0 = w1q + (2 * t) * 41;     // s_load
            const uint32* __restrict__ w1 = w1q + (2 * t + 1) * 41;
            float a0 = 0.f, a1 = 0.f;
#pragma unroll
            for (int p = 0; p < 41; ++p) {
                a0 = fdot2(fh[p], w0[p], a0);
                a1 = fdot2(fh[p], w1[p], a1);
            }
            wd[p4] = pkh2(a0, a1);
        }
        *(uint4*)(hrow + 4 * g) = make_uint4(wd[0], wd[1], wd[2], wd[3]);
    }
}

__global__ __launch_bounds__(256) void k_stats(
    const uint4* __restrict__ h4, float* __restrict__ gstats, int N)
{
    const int tid = threadIdx.x;
    const int g = tid & 7;                  // word-group, constant per thread
    float s[8], q[8];
#pragma unroll
    for (int e = 0; e < 8; ++e) { s[e] = 0.f; q[e] = 0.f; }
    const int total = N * 8;
    for (int i = blockIdx.x * 256 + tid; i < total; i += gridDim.x * 256) {
        const uint4 u = h4[i];              // i&7 == g always (stride%8==0)
        float lo, hi;
        unpk(u.x, lo, hi); s[0]+=lo; q[0]=fmaf(lo,lo,q[0]); s[1]+=hi; q[1]=fmaf(hi,hi,q[1]);
        unpk(u.y, lo, hi); s[2]+=lo; q[2]=fmaf(lo,lo,q[2]); s[3]+=hi; q[3]=fmaf(hi,hi,q[3]);
        unpk(u.z, lo, hi); s[4]+=lo; q[4]=fmaf(lo,lo,q[4]); s[5]+=hi; q[5]=fmaf(hi,hi,q[5]);
        unpk(u.w, lo, hi); s[6]+=lo; q[6]=fmaf(lo,lo,q[6]); s[7]+=hi; q[7]=fmaf(hi,hi,q[7]);
    }
    // reduce across lanes sharing g: xor 8,16,32 keeps low-3-bits
#pragma unroll
    for (int e = 0; e < 8; ++e) {
        for (int m = 8; m < 64; m <<= 1) {
            s[e] += __shfl_xor(s[e], m);
            q[e] += __shfl_xor(q[e], m);
        }
    }
    __shared__ float sred[4][8][8], qred[4][8][8];
    const int wib = tid >> 6, lane = tid & 63;
    if (lane < 8) {
#pragma unroll
        for (int e = 0; e < 8; ++e) { sred[wib][lane][e] = s[e]; qred[wib][lane][e] = q[e]; }
    }
    __syncthreads();
    if (tid < 64) {
        const int gg = tid >> 3, e = tid & 7;
        atomicAdd(&gstats[tid], sred[0][gg][e] + sred[1][gg][e]
                              + sred[2][gg][e] + sred[3][gg][e]);
    } else if (tid < 128) {
        const int d = tid - 64, gg = d >> 3, e = d & 7;
        atomicAdd(&gstats[64 + d], qred[0][gg][e] + qred[1][gg][e]
                                 + qred[2][gg][e] + qred[3][gg][e]);
    }
}

__global__ void k_bn(const float* __restrict__ gstats,
                     const float* __restrict__ gamma,
                     const float* __restrict__ beta,
                     float* __restrict__ sc_sh, float invN)
{
    const int d = threadIdx.x;  // 64 threads
    const float mu  = gstats[d] * invN;
    const float var = gstats[64 + d] * invN - mu * mu;
    const float sc  = gamma[d] * rsqrtf(var + 1e-5f);
    sc_sh[d]      = sc;
    sc_sh[64 + d] = beta[d] - mu * sc;
}

__global__ __launch_bounds__(256) void k_apply(
    uint4* __restrict__ h4, const float* __restrict__ sc_sh, int N)
{
    const int tid = threadIdx.x;
    const int g = tid & 7;                  // fixed word-group
    float sc[8], sh[8];
#pragma unroll
    for (int e = 0; e < 8; ++e) {
        sc[e] = sc_sh[8 * g + e];
        sh[e] = sc_sh[64 + 8 * g + e];
    }
    const int total = N * 8;
    for (int i = blockIdx.x * 256 + tid; i < total; i += gridDim.x * 256) {
        uint4 u = h4[i];
        float lo, hi; uint4 r;
        unpk(u.x, lo, hi);
        r.x = pkh2(fmaxf(fmaf(lo, sc[0], sh[0]), 0.f), fmaxf(fmaf(hi, sc[1], sh[1]), 0.f));
        unpk(u.y, lo, hi);
        r.y = pkh2(fmaxf(fmaf(lo, sc[2], sh[2]), 0.f), fmaxf(fmaf(hi, sc[3], sh[3]), 0.f));
        unpk(u.z, lo, hi);
        r.z = pkh2(fmaxf(fmaf(lo, sc[4], sh[4]), 0.f), fmaxf(fmaf(hi, sc[5], sh[5]), 0.f));
        unpk(u.w, lo, hi);
        r.w = pkh2(fmaxf(fmaf(lo, sc[6], sh[6]), 0.f), fmaxf(fmaf(hi, sc[7], sh[7]), 0.f));
        h4[i] = r;
    }
}

__global__ __launch_bounds__(256, 6) void k_conv2(
    const uint4* __restrict__ h4, const uint32* __restrict__ w2q,
    const int* __restrict__ nbr, float* __restrict__ out,
    int N, int nblk)
{
    // bijective chunked XCD swizzle (9 gather regions stay in one XCD L2)
    const int bid = blockIdx.x;
    const int qq = nblk >> 3, rr = nblk & 7;
    const int xcd = bid & 7, pos = bid >> 3;
    const int sb = (xcd < rr) ? xcd * (qq + 1) + pos
                              : rr * (qq + 1) + (xcd - rr) * qq + pos;
    const int lane = threadIdx.x & 63;
    const int tile = sb * 4 + (threadIdx.x >> 6);
    const long long n0 = (long long)tile * 64;
    if (n0 >= N) return;
    const int n = (int)(n0 + lane);

    float a0 = 0.f, a1 = 0.f, a2 = 0.f;
    int jn = nbr[n];                                   // prefetch k=0
    for (int k = 0; k < KVOL; ++k) {
        const int j = (jn < 0) ? N : jn;               // zero-row redirect
        if (k + 1 < KVOL) jn = nbr[(long long)(k + 1) * N + n];

        const uint4* __restrict__ row = h4 + (long long)j * 8;
        uint4 u[8];
#pragma unroll
        for (int g = 0; g < 8; ++g) u[g] = row[g];     // one 128B line/lane

        const uint32* __restrict__ w = w2q + k * 96;   // uniform -> s_load
#pragma unroll
        for (int g = 0; g < 8; ++g) {
            const int wb = g * 12;
            a0 = fdot2(u[g].x, w[wb + 0], a0);
            a1 = fdot2(u[g].x, w[wb + 4], a1);
            a2 = fdot2(u[g].x, w[wb + 8], a2);
            a0 = fdot2(u[g].y, w[wb + 1], a0);
            a1 = fdot2(u[g].y, w[wb + 5], a1);
            a2 = fdot2(u[g].y, w[wb + 9], a2);
            a0 = fdot2(u[g].z, w[wb + 2], a0);
            a1 = fdot2(u[g].z, w[wb + 6], a1);
            a2 = fdot2(u[g].z, w[wb + 10], a2);
            a0 = fdot2(u[g].w, w[wb + 3], a0);
            a1 = fdot2(u[g].w, w[wb + 7], a1);
            a2 = fdot2(u[g].w, w[wb + 11], a2);
        }
    }
    out[3LL * n + 0] = a0;
    out[3LL * n + 1] = a1;
    out[3LL * n + 2] = a2;
}

extern "C" void kernel_launch(void* const* d_in, const int* in_sizes, int n_in,
                              void* d_out, int out_size, void* d_ws, size_t ws_size,
                              hipStream_t stream) {
    const float* feats = (const float*)d_in[0];
    const float* W1    = (const float*)d_in[1];
    const float* gamma = (const float*)d_in[2];
    const float* beta  = (const float*)d_in[3];
    const float* W2    = (const float*)d_in[4];
    const int*   nbr   = (const int*)  d_in[5];
    const int N  = in_sizes[0] / 3;
    const int Ns = N + 64;
    float* out = (float*)d_out;

    char* ws = (char*)d_ws;
    uint32* h32 = (uint32*)ws;                                  // (N+1)*128 B
    size_t off = (((size_t)(N + 1) * 128) + 255) & ~(size_t)255;
    float* f_t = (float*)(ws + off); off += (size_t)3 * Ns * 4;
    uint32* w1q = (uint32*)(ws + off); off += (size_t)64 * 41 * 4;
    uint32* w2q = (uint32*)(ws + off); off += (size_t)KVOL * 96 * 4;
    float* gstats = (float*)(ws + off);                         // 128 f32
    float* sc_sh  = gstats + 128;

    (void)hipMemsetAsync(gstats, 0, 128 * sizeof(float), stream);

    const int nblk = (N / 64 + 3) / 4;            // 3907

    k_prep <<<257, 256, 0, stream>>>(feats, W1, W2, f_t, w1q, w2q, h32, N, Ns);
    k_conv1<<<nblk, 256, 0, stream>>>(f_t, w1q, nbr, h32, N, Ns);
    k_stats<<<2048, 256, 0, stream>>>((const uint4*)h32, gstats, N);
    k_bn   <<<1, 64, 0, stream>>>(gstats, gamma, beta, sc_sh, 1.0f / (float)N);
    k_apply<<<2048, 256, 0, stream>>>((uint4*)h32, sc_sh, N);
    k_conv2<<<nblk, 256, 0, stream>>>((const uint4*)h32, w2q, nbr, out, N, nblk);
}